// Round 3
// baseline (215.787 us; speedup 1.0000x reference)
//
#include <hip/hip_runtime.h>

// ---------------------------------------------------------------------------
// DigitConvolutionalModel: x(32768,784) -> conv3x3(valid) -> 676
//   -> relu(@W1(676,300)+b1) -> relu(@W2(300,300)+b2) -> @W3(300,10)+b3
//
// R3: split at h1. conv folded into W1eff (784->800 K-pad, 300->320 N-pad).
//  prep:  weights -> bf16 MFMA B-frag order (16x16x32) in d_ws.
//  gemm1: x @ W1eff + b1, relu -> h1 bf16 ROW-MAJOR [32768][320] in d_ws.
//         A: global->regs (fp32->bf16 cvt), B: stage16 dbuf, 25 barriers.
//         LDS 40KB only.
//  gemm23: h1 @ W2 + b2, relu -> (LDS exchange) -> @ W3 + b3 -> out.
//         A: h1 rows are bf16, one dwordx4 IS an A-frag (no cvt, L3-hot).
//         B2: stage16 dbuf (40KB, reused as h2 exchange). W3: global->regs.
// ---------------------------------------------------------------------------

typedef __bf16 bf16_t;
typedef __bf16 bf16x8 __attribute__((ext_vector_type(8)));
typedef float  f32x4  __attribute__((ext_vector_type(4)));

#define MFMA16(a, b, c) __builtin_amdgcn_mfma_f32_16x16x32_bf16((a), (b), (c), 0, 0, 0)

#define W1F_ELEMS (25 * 20 * 64 * 8)  // 256000  (K=800, N=320)
#define W2F_ELEMS (10 * 20 * 64 * 8)  // 102400  (K=320, N=320)
#define W3F_ELEMS (10 * 1 * 64 * 8)   // 5120    (K=320, N=16)
#define H1_OFF    768000              // byte offset of h1 in ws (256-aligned)
#define H1_BYTES  ((size_t)32768 * 320 * 2)

// ---------------------------------------------------------------------------
__global__ void prep_weights(const float* __restrict__ conv_w,
                             const float* __restrict__ W1,
                             const float* __restrict__ W2,
                             const float* __restrict__ W3,
                             bf16_t* __restrict__ W1f,
                             bf16_t* __restrict__ W2f,
                             bf16_t* __restrict__ W3f) {
    int idx = blockIdx.x * 256 + threadIdx.x;
    if (idx < 800 * 320) {
        int k = idx / 320;
        int n = idx - k * 320;
        float v = 0.0f;
        if (k < 784 && n < 300) {
            int py = k / 28;
            int px = k - py * 28;
#pragma unroll
            for (int ky = 0; ky < 3; ++ky) {
                int oy = py - ky;
                if (oy < 0 || oy > 25) continue;
#pragma unroll
                for (int kx = 0; kx < 3; ++kx) {
                    int ox = px - kx;
                    if (ox < 0 || ox > 25) continue;
                    v += conv_w[ky * 3 + kx] * W1[(oy * 26 + ox) * 300 + n];
                }
            }
        }
        int kc = k >> 5, quad = (k >> 3) & 3, j = k & 7;
        int nt = n >> 4, nin = n & 15;
        W1f[(((kc * 20 + nt) * 64 + quad * 16 + nin) << 3) + j] = (bf16_t)v;
    } else if (idx < 800 * 320 + 320 * 320) {
        int i2 = idx - 800 * 320;
        int k = i2 / 320;
        int n = i2 - k * 320;
        float v = (k < 300 && n < 300) ? W2[k * 300 + n] : 0.0f;
        int kc = k >> 5, quad = (k >> 3) & 3, j = k & 7;
        int nt = n >> 4, nin = n & 15;
        W2f[(((kc * 20 + nt) * 64 + quad * 16 + nin) << 3) + j] = (bf16_t)v;
    } else if (idx < 800 * 320 + 320 * 320 + 320 * 16) {
        int i3 = idx - (800 * 320 + 320 * 320);
        int k = i3 / 16;
        int n = i3 - k * 16;
        float v = (k < 300 && n < 10) ? W3[k * 10 + n] : 0.0f;
        int kc = k >> 5, quad = (k >> 3) & 3, j = k & 7;
        W3f[(((kc * 64) + quad * 16 + n) << 3) + j] = (bf16_t)v;
    }
}

// async global -> LDS, 16B/lane; lds base wave-uniform.
__device__ __forceinline__ void stage16(const bf16x8* g, bf16x8* l) {
    __builtin_amdgcn_global_load_lds(
        (const __attribute__((address_space(1))) void*)g,
        (__attribute__((address_space(3))) void*)l, 16, 0, 0);
}

// ---------------------------------------------------------------------------
// K1: h1 = relu(x @ W1eff + b1), h1 bf16 row-major [.][320].
// 64 rows/block, 512 thr = 8 waves; wave: mh=w&1 (rows mh*32..+31),
// nq=w>>1 (n-tiles nq*5..+4). LDS = 40KB B-dbuf only.
// ---------------------------------------------------------------------------
__global__ __launch_bounds__(512, 4) void gemm1(
    const float* __restrict__ x, const float* __restrict__ b1,
    const bf16x8* __restrict__ W1f, bf16_t* __restrict__ h1) {
    __shared__ bf16x8 bufB[2 * 1280];  // 40KB double buffer

    const int tid = threadIdx.x;
    const int w   = tid >> 6;
    const int l   = tid & 63;
    const int mh  = w & 1;
    const int nq  = w >> 1;
    const int q   = l >> 4;
    const int l15 = l & 15;
    const int r0  = blockIdx.x * 64;

    const float* rowA = x + (size_t)(r0 + mh * 32 + l15) * 784;
    const float* rowB = rowA + 16 * 784;

    // prologue: stage chunk 0, prefetch A chunk 0
    for (int t = w; t < 20; t += 8) stage16(W1f + (t * 64 + l), bufB + t * 64);
    float4 ua0, ua1, ub0, ub1;
    {
        const float4* pa = (const float4*)(rowA + q * 8);
        const float4* pb = (const float4*)(rowB + q * 8);
        ua0 = pa[0]; ua1 = pa[1]; ub0 = pb[0]; ub1 = pb[1];
    }

    f32x4 acc[2][5];
#pragma unroll
    for (int m = 0; m < 2; ++m)
#pragma unroll
        for (int nt = 0; nt < 5; ++nt) acc[m][nt] = (f32x4){0.f, 0.f, 0.f, 0.f};

    for (int kc = 0; kc < 25; ++kc) {
        __syncthreads();

        if (kc + 1 < 25) {
            int s1 = (kc + 1) & 1;
            for (int t = w; t < 20; t += 8)
                stage16(W1f + (((kc + 1) * 20 + t) * 64 + l),
                        bufB + s1 * 1280 + t * 64);
        }

        bf16x8 afA, afB;
        afA[0] = (bf16_t)ua0.x; afA[1] = (bf16_t)ua0.y;
        afA[2] = (bf16_t)ua0.z; afA[3] = (bf16_t)ua0.w;
        afA[4] = (bf16_t)ua1.x; afA[5] = (bf16_t)ua1.y;
        afA[6] = (bf16_t)ua1.z; afA[7] = (bf16_t)ua1.w;
        afB[0] = (bf16_t)ub0.x; afB[1] = (bf16_t)ub0.y;
        afB[2] = (bf16_t)ub0.z; afB[3] = (bf16_t)ub0.w;
        afB[4] = (bf16_t)ub1.x; afB[5] = (bf16_t)ub1.y;
        afB[6] = (bf16_t)ub1.z; afB[7] = (bf16_t)ub1.w;

        if (kc + 1 < 25) {
            int k0 = (kc + 1) * 32 + q * 8;
            if (k0 < 784) {
                const float4* pa = (const float4*)(rowA + k0);
                const float4* pb = (const float4*)(rowB + k0);
                ua0 = pa[0]; ua1 = pa[1]; ub0 = pb[0]; ub1 = pb[1];
            } else {
                ua0 = ua1 = ub0 = ub1 = make_float4(0.f, 0.f, 0.f, 0.f);
            }
        }

        const bf16x8* bb = bufB + (kc & 1) * 1280 + (nq * 5) * 64 + l;
#pragma unroll
        for (int nt = 0; nt < 5; ++nt) {
            bf16x8 b = bb[nt * 64];
            acc[0][nt] = MFMA16(afA, b, acc[0][nt]);
            acc[1][nt] = MFMA16(afB, b, acc[1][nt]);
        }
    }

    // epilogue: bias + relu -> h1 bf16 row-major (16-lane 32B runs)
#pragma unroll
    for (int nt = 0; nt < 5; ++nt) {
        int n = (nq * 5 + nt) * 16 + l15;
        float bias = (n < 300) ? b1[n] : 0.0f;
#pragma unroll
        for (int mt2 = 0; mt2 < 2; ++mt2) {
            int mt = mh * 2 + mt2;
#pragma unroll
            for (int r = 0; r < 4; ++r) {
                float v = acc[mt2][nt][r] + bias;
                v = v > 0.f ? v : 0.f;
                h1[(size_t)(r0 + mt * 16 + q * 4 + r) * 320 + n] = (bf16_t)v;
            }
        }
    }
}

// ---------------------------------------------------------------------------
// K2: out = relu(h1 @ W2 + b2) @ W3 + b3.
// Same wave mapping as K1. A-frags load directly from bf16 h1 rows (one
// dwordx4 = one frag, no cvt). LDS 40KB: B2 dbuf, reused for h2 exchange.
// ---------------------------------------------------------------------------
__global__ __launch_bounds__(512, 4) void gemm23(
    const bf16_t* __restrict__ h1, const float* __restrict__ b2,
    const float* __restrict__ b3, const bf16x8* __restrict__ W2f,
    const bf16x8* __restrict__ W3f, float* __restrict__ out) {
    __shared__ bf16x8 arena[2560];  // 40KB: B2 dbuf -> h2 exchange

    const int tid = threadIdx.x;
    const int w   = tid >> 6;
    const int l   = tid & 63;
    const int mh  = w & 1;
    const int nq  = w >> 1;
    const int q   = l >> 4;
    const int l15 = l & 15;
    const int r0  = blockIdx.x * 64;

    const bf16_t* rowA = h1 + (size_t)(r0 + mh * 32 + l15) * 320;
    const bf16_t* rowB = rowA + 16 * 320;

    for (int t = w; t < 20; t += 8) stage16(W2f + (t * 64 + l), arena + t * 64);
    bf16x8 uaA = *(const bf16x8*)(rowA + q * 8);
    bf16x8 uaB = *(const bf16x8*)(rowB + q * 8);

    f32x4 acc[2][5];
#pragma unroll
    for (int m = 0; m < 2; ++m)
#pragma unroll
        for (int nt = 0; nt < 5; ++nt) acc[m][nt] = (f32x4){0.f, 0.f, 0.f, 0.f};

    for (int kc = 0; kc < 10; ++kc) {
        __syncthreads();

        if (kc + 1 < 10) {
            int s1 = (kc + 1) & 1;
            for (int t = w; t < 20; t += 8)
                stage16(W2f + (((kc + 1) * 20 + t) * 64 + l),
                        arena + s1 * 1280 + t * 64);
        }

        bf16x8 afA = uaA, afB = uaB;
        if (kc + 1 < 10) {
            uaA = *(const bf16x8*)(rowA + (kc + 1) * 32 + q * 8);
            uaB = *(const bf16x8*)(rowB + (kc + 1) * 32 + q * 8);
        }

        const bf16x8* bb = arena + (kc & 1) * 1280 + (nq * 5) * 64 + l;
#pragma unroll
        for (int nt = 0; nt < 5; ++nt) {
            bf16x8 b = bb[nt * 64];
            acc[0][nt] = MFMA16(afA, b, acc[0][nt]);
            acc[1][nt] = MFMA16(afB, b, acc[1][nt]);
        }
    }
    __syncthreads();  // done reading arena (B2)

    // h2 = relu(acc + b2) -> arena as A-frags [kc2][mt][64][8]
    {
        bf16_t* hb = (bf16_t*)arena;
#pragma unroll
        for (int nt = 0; nt < 5; ++nt) {
            int n = (nq * 5 + nt) * 16 + l15;
            float bias = (n < 300) ? b2[n] : 0.0f;
            int kc2 = n >> 5, quad = (n >> 3) & 3, j = n & 7;
#pragma unroll
            for (int mt2 = 0; mt2 < 2; ++mt2) {
                int mt = mh * 2 + mt2;
#pragma unroll
                for (int r = 0; r < 4; ++r) {
                    float v = acc[mt2][nt][r] + bias;
                    v = v > 0.f ? v : 0.f;
                    hb[(((kc2 * 4 + mt) * 64 + quad * 16 + q * 4 + r) << 3) + j] =
                        (bf16_t)v;
                }
            }
        }
    }
    __syncthreads();

    // GEMM3: waves 0-3 (mt = w), W3 B-frags straight from global (L2-hot)
    if (w < 4) {
        f32x4 acc3 = (f32x4){0.f, 0.f, 0.f, 0.f};
        for (int kc = 0; kc < 10; ++kc) {
            bf16x8 a = arena[(kc * 4 + w) * 64 + l];
            bf16x8 b = W3f[kc * 64 + l];
            acc3 = MFMA16(a, b, acc3);
        }
        if (l15 < 10) {
            float bias = b3[l15];
#pragma unroll
            for (int r = 0; r < 4; ++r)
                out[(size_t)(r0 + w * 16 + q * 4 + r) * 10 + l15] = acc3[r] + bias;
        }
    }
}

// ---------------------------------------------------------------------------
extern "C" void kernel_launch(void* const* d_in, const int* in_sizes, int n_in,
                              void* d_out, int out_size, void* d_ws, size_t ws_size,
                              hipStream_t stream) {
    const float* x      = (const float*)d_in[0];
    const float* conv_w = (const float*)d_in[1];
    const float* W1     = (const float*)d_in[2];
    const float* b1     = (const float*)d_in[3];
    const float* W2     = (const float*)d_in[4];
    const float* b2     = (const float*)d_in[5];
    const float* W3     = (const float*)d_in[6];
    const float* b3     = (const float*)d_in[7];
    float* out = (float*)d_out;

    char* ws = (char*)d_ws;
    bf16_t* W1f = (bf16_t*)(ws);
    bf16_t* W2f = (bf16_t*)(ws + (size_t)W1F_ELEMS * 2);
    bf16_t* W3f = (bf16_t*)(ws + (size_t)(W1F_ELEMS + W2F_ELEMS) * 2);
    bf16_t* h1  = (bf16_t*)(ws + H1_OFF);
    if (ws_size < H1_OFF + H1_BYTES) return;  // need ~21.7 MB scratch

    int prep_total = 800 * 320 + 320 * 320 + 320 * 16;  // 363520
    prep_weights<<<(prep_total + 255) / 256, 256, 0, stream>>>(
        conv_w, W1, W2, W3, W1f, W2f, W3f);

    gemm1<<<32768 / 64, 512, 0, stream>>>(x, b1, (const bf16x8*)W1f, h1);

    gemm23<<<32768 / 64, 512, 0, stream>>>(
        h1, b2, b3, (const bf16x8*)W2f, (const bf16x8*)W3f, out);
}